// Round 1
// baseline (455.245 us; speedup 1.0000x reference)
//
#include <hip/hip_runtime.h>

// Problem constants
#define BATCH 8
#define IMH 96
#define IMW 96
#define CH 32
#define NKP 21
#define TILE 16
#define HALO 18           // TILE + 2
#define PITCH 33          // pixel pitch in LDS floats (bank-conflict pad)

__global__ void __launch_bounds__(256)
ckp_fused_kernel(const float* __restrict__ x,
                 const float* __restrict__ w2, const float* __restrict__ b2,
                 const float* __restrict__ wa, const float* __restrict__ ba,
                 const float* __restrict__ wb, const float* __restrict__ bb,
                 const float* __restrict__ Wp,
                 float* __restrict__ out)
{
    __shared__ float sH[HALO * HALO * PITCH]; // h halo tile, [pix][c] pitch 33
    __shared__ float sFsum[TILE * TILE];
    __shared__ float sWv[CH];

    const int tid  = threadIdx.x;
    const int tile = blockIdx.x;          // 0..35
    const int b    = blockIdx.y;          // 0..7
    const int n    = blockIdx.z;          // 0..20
    const int ty0  = (tile / (IMW / TILE)) * TILE;
    const int tx0  = (tile % (IMW / TILE)) * TILE;

    // wv[c] = sum_d Wp[n][c][d]
    if (tid < CH) {
        const float* wp = Wp + (n * CH + tid) * CH;
        float s = 0.f;
        #pragma unroll
        for (int d = 0; d < CH; ++d) s += wp[d];
        sWv[tid] = s;
    }

    const float* wan = wa + n * CH * CH;
    const float* ban = ba + n * CH;

    // ---- Phase 1: halo pixels -> f -> h -> LDS ----
    for (int p = tid; p < HALO * HALO; p += 256) {
        const int hy = p / HALO, hx = p % HALO;
        const int Y = ty0 + hy - 1, X = tx0 + hx - 1;
        float* dst = &sH[p * PITCH];
        if (Y >= 0 && Y < IMH && X >= 0 && X < IMW) {
            const float* xp = x + (((size_t)b * IMH + Y) * IMW + X) * CH;
            float xv[CH];
            #pragma unroll
            for (int e = 0; e < CH; e += 4) {
                float4 v = *(const float4*)(xp + e);
                xv[e] = v.x; xv[e+1] = v.y; xv[e+2] = v.z; xv[e+3] = v.w;
            }
            // f = relu(x @ w2 + b2)
            float f[CH];
            #pragma unroll
            for (int c = 0; c < CH; ++c) f[c] = b2[c];
            #pragma unroll
            for (int e = 0; e < CH; ++e) {
                const float xe = xv[e];
                const float* wr = w2 + e * CH;
                #pragma unroll
                for (int c = 0; c < CH; ++c) f[c] = fmaf(xe, wr[c], f[c]);
            }
            float fs = 0.f;
            #pragma unroll
            for (int c = 0; c < CH; ++c) { f[c] = fmaxf(f[c], 0.f); fs += f[c]; }
            if (hy >= 1 && hy <= TILE && hx >= 1 && hx <= TILE)
                sFsum[(hy - 1) * TILE + (hx - 1)] = fs;
            // h = relu(f @ wa[n] + ba[n])
            float h[CH];
            #pragma unroll
            for (int c = 0; c < CH; ++c) h[c] = ban[c];
            #pragma unroll
            for (int e = 0; e < CH; ++e) {
                const float fe = f[e];
                const float* wr = wan + e * CH;
                #pragma unroll
                for (int c = 0; c < CH; ++c) h[c] = fmaf(fe, wr[c], h[c]);
            }
            #pragma unroll
            for (int c = 0; c < CH; ++c) dst[c] = fmaxf(h[c], 0.f);
        } else {
            #pragma unroll
            for (int c = 0; c < CH; ++c) dst[c] = 0.f;  // SAME zero-padding of h
        }
    }
    __syncthreads();

    // ---- Phase 2: per inner pixel, 3x3 conv g + dot with wv ----
    const int iy = tid / TILE, ix = tid % TILE;
    const float* wbn = wb + n * 9 * CH * CH;
    const float* bbn = bb + n * CH;
    float g[CH];
    #pragma unroll
    for (int c = 0; c < CH; ++c) g[c] = bbn[c];
    for (int dy = 0; dy < 3; ++dy) {
        for (int dx = 0; dx < 3; ++dx) {
            const float* hrow = &sH[((iy + dy) * HALO + (ix + dx)) * PITCH];
            const float* wr0 = wbn + (dy * 3 + dx) * CH * CH;
            #pragma unroll
            for (int e = 0; e < CH; ++e) {
                const float hv = hrow[e];
                const float* wr = wr0 + e * CH;
                #pragma unroll
                for (int c = 0; c < CH; ++c) g[c] = fmaf(hv, wr[c], g[c]);
            }
        }
    }
    float lsum = 0.f;
    #pragma unroll
    for (int c = 0; c < CH; ++c) lsum = fmaf(fmaxf(g[c], 0.f), sWv[c], lsum);

    const int Y = ty0 + iy, X = tx0 + ix;
    out[(((size_t)b * IMH + Y) * IMW + X) * NKP + n] = sFsum[tid] + lsum;
}

extern "C" void kernel_launch(void* const* d_in, const int* in_sizes, int n_in,
                              void* d_out, int out_size, void* d_ws, size_t ws_size,
                              hipStream_t stream) {
    const float* x  = (const float*)d_in[0];
    const float* w2 = (const float*)d_in[1];
    const float* b2 = (const float*)d_in[2];
    const float* wa = (const float*)d_in[3];
    const float* ba = (const float*)d_in[4];
    const float* wb = (const float*)d_in[5];
    const float* bb = (const float*)d_in[6];
    const float* Wp = (const float*)d_in[7];
    float* out = (float*)d_out;

    dim3 grid((IMH / TILE) * (IMW / TILE), BATCH, NKP); // 36 x 8 x 21
    dim3 block(256);
    ckp_fused_kernel<<<grid, block, 0, stream>>>(x, w2, b2, wa, ba, wb, bb, Wp, out);
}

// Round 2
// 123.601 us; speedup vs baseline: 3.6832x; 3.6832x over previous
//
#include <hip/hip_runtime.h>

// Problem constants
#define BATCH 8
#define IMH 96
#define IMW 96
#define CH 32
#define NKP 21
#define TILE 16
#define HALO 18           // TILE + 2
#define FPITCH 40         // bf16 per pixel in LDS (80 B row stride -> 20-bank shift, <=2-way conflicts)
#define NPIX 324          // HALO*HALO
#define NPIX_PAD 336      // padded to 21 m-tiles of 16

typedef __bf16 bf16x8 __attribute__((ext_vector_type(8)));
typedef float  f32x4  __attribute__((ext_vector_type(4)));

static __device__ inline f32x4 mfma16(bf16x8 a, bf16x8 b, f32x4 c) {
    return __builtin_amdgcn_mfma_f32_16x16x32_bf16(a, b, c, 0, 0, 0);
}

// ---------------- Kernel 1: f = relu(x @ w2 + b2), once; store bf16 f + fp32 fsum ----
__global__ void __launch_bounds__(256)
f_precompute_kernel(const float* __restrict__ x,
                    const float* __restrict__ w2, const float* __restrict__ b2,
                    __bf16* __restrict__ fout, float* __restrict__ fsum_out)
{
    const int gp = blockIdx.x * 256 + threadIdx.x;   // pixel id, 0..73727
    const float* xp = x + (size_t)gp * CH;
    float xv[CH];
    #pragma unroll
    for (int e = 0; e < CH; e += 4) {
        float4 v = *(const float4*)(xp + e);
        xv[e] = v.x; xv[e+1] = v.y; xv[e+2] = v.z; xv[e+3] = v.w;
    }
    float f[CH];
    #pragma unroll
    for (int c = 0; c < CH; ++c) f[c] = b2[c];
    #pragma unroll
    for (int e = 0; e < CH; ++e) {
        const float xe = xv[e];
        const float* wr = w2 + e * CH;
        #pragma unroll
        for (int c = 0; c < CH; ++c) f[c] = fmaf(xe, wr[c], f[c]);
    }
    float fs = 0.f;
    #pragma unroll
    for (int c = 0; c < CH; ++c) { f[c] = fmaxf(f[c], 0.f); fs += f[c]; }
    #pragma unroll
    for (int q = 0; q < 4; ++q) {
        bf16x8 v;
        #pragma unroll
        for (int j = 0; j < 8; ++j) v[j] = (__bf16)f[q * 8 + j];
        *(bf16x8*)&fout[(size_t)gp * CH + q * 8] = v;
    }
    fsum_out[gp] = fs;
}

// ---------------- Kernel 2: per (tile, b, n): h = relu(f@wa+ba) via MFMA, 3x3 conv via MFMA ----
__global__ void __launch_bounds__(256)
ckp_mfma_kernel(const __bf16* __restrict__ fws, const float* __restrict__ fsum_ws,
                const float* __restrict__ wa, const float* __restrict__ ba,
                const float* __restrict__ wb, const float* __restrict__ bb,
                const float* __restrict__ Wp, float* __restrict__ out)
{
    __shared__ __bf16 sF[NPIX_PAD * FPITCH];
    __shared__ __bf16 sH[NPIX_PAD * FPITCH];
    __shared__ float  sFsum[TILE * TILE];

    const int tid  = threadIdx.x;
    const int tile = blockIdx.x;          // 0..35
    const int b    = blockIdx.y;          // 0..7
    const int n    = blockIdx.z;          // 0..20
    const int ty0  = (tile / (IMW / TILE)) * TILE;
    const int tx0  = (tile % (IMW / TILE)) * TILE;

    const int lane = tid & 63;
    const int w    = tid >> 6;            // wave id 0..3
    const int r4   = lane & 15;           // A-row / C-col index
    const int g16  = lane >> 4;           // lane group 0..3
    const int kb   = g16 * 8;             // K base for A/B fragments

    // ---- stage bf16 f halo into LDS (zero-pad OOB) ----
    for (int i = tid; i < NPIX * 4; i += 256) {
        const int p = i >> 2, q = i & 3;
        const int hy = p / HALO, hx = p % HALO;
        const int Y = ty0 + hy - 1, X = tx0 + hx - 1;
        bf16x8 v;
        if (Y >= 0 && Y < IMH && X >= 0 && X < IMW) {
            v = *(const bf16x8*)&fws[(((size_t)b * IMH + Y) * IMW + X) * CH + q * 8];
        } else {
            #pragma unroll
            for (int j = 0; j < 8; ++j) v[j] = (__bf16)0.f;
        }
        *(bf16x8*)&sF[p * FPITCH + q * 8] = v;
    }
    if (tid < 48) {  // zero the 12 pad pixels (324..335)
        bf16x8 z;
        #pragma unroll
        for (int j = 0; j < 8; ++j) z[j] = (__bf16)0.f;
        *(bf16x8*)&sF[(NPIX + (tid >> 2)) * FPITCH + (tid & 3) * 8] = z;
    }
    // stage fsum for the inner 16x16
    {
        const int iy = tid >> 4, ix = tid & 15;
        sFsum[tid] = fsum_ws[((size_t)b * IMH + ty0 + iy) * IMW + tx0 + ix];
    }

    // ---- load B fragments: wa (2 halves), wb (9 taps x 2 halves), fp32 -> bf16 ----
    const float* wan = wa + n * CH * CH;
    bf16x8 wafr[2];
    #pragma unroll
    for (int hf = 0; hf < 2; ++hf)
        #pragma unroll
        for (int j = 0; j < 8; ++j)
            wafr[hf][j] = (__bf16)wan[(kb + j) * CH + r4 + hf * 16];

    const float* wbn = wb + (size_t)n * 9 * CH * CH;
    bf16x8 wbfr[9][2];
    #pragma unroll
    for (int t = 0; t < 9; ++t)
        #pragma unroll
        for (int hf = 0; hf < 2; ++hf)
            #pragma unroll
            for (int j = 0; j < 8; ++j)
                wbfr[t][hf][j] = (__bf16)wbn[(t * CH + kb + j) * CH + r4 + hf * 16];

    const float* ban = ba + n * CH;
    const float ba0 = ban[r4], ba1 = ban[r4 + 16];

    __syncthreads();

    // ---- h-phase: h = relu(f @ wa + ba), 21 m-tiles of 16 halo pixels, 4 waves ----
    for (int t = w; t < 21; t += 4) {
        bf16x8 afr = *(const bf16x8*)&sF[(t * 16 + r4) * FPITCH + kb];
        f32x4 acc0 = {0.f, 0.f, 0.f, 0.f};
        f32x4 acc1 = {0.f, 0.f, 0.f, 0.f};
        acc0 = mfma16(afr, wafr[0], acc0);
        acc1 = mfma16(afr, wafr[1], acc1);
        #pragma unroll
        for (int reg = 0; reg < 4; ++reg) {
            const int p = t * 16 + g16 * 4 + reg;
            sH[p * FPITCH + r4]      = (__bf16)fmaxf(acc0[reg] + ba0, 0.f);
            sH[p * FPITCH + r4 + 16] = (__bf16)fmaxf(acc1[reg] + ba1, 0.f);
        }
    }

    // epilogue scalars (overlap with h-phase latency)
    const float* bbn = bb + n * CH;
    const float bb0 = bbn[r4], bb1 = bbn[r4 + 16];
    const float* wpn = Wp + n * CH * CH;
    float wv0 = 0.f, wv1 = 0.f;
    #pragma unroll
    for (int d = 0; d < CH; ++d) {
        wv0 += wpn[r4 * CH + d];
        wv1 += wpn[(r4 + 16) * CH + d];
    }

    __syncthreads();

    // ---- conv phase: g = relu(conv3x3(h) + bb); lsum = g . wv ; 2 rows in flight ----
    #pragma unroll
    for (int ii = 0; ii < 2; ++ii) {
        const int iyA = w * 4 + ii * 2;
        const int iyB = iyA + 1;
        f32x4 aA0 = {0.f,0.f,0.f,0.f}, aA1 = {0.f,0.f,0.f,0.f};
        f32x4 aB0 = {0.f,0.f,0.f,0.f}, aB1 = {0.f,0.f,0.f,0.f};
        #pragma unroll
        for (int dy = 0; dy < 3; ++dy) {
            #pragma unroll
            for (int dx = 0; dx < 3; ++dx) {
                const int t = dy * 3 + dx;
                const int pA = (iyA + dy) * HALO + r4 + dx;
                const int pB = (iyB + dy) * HALO + r4 + dx;
                bf16x8 frA = *(const bf16x8*)&sH[pA * FPITCH + kb];
                bf16x8 frB = *(const bf16x8*)&sH[pB * FPITCH + kb];
                aA0 = mfma16(frA, wbfr[t][0], aA0);
                aA1 = mfma16(frA, wbfr[t][1], aA1);
                aB0 = mfma16(frB, wbfr[t][0], aB0);
                aB1 = mfma16(frB, wbfr[t][1], aB1);
            }
        }
        // epilogue for both rows
        #pragma unroll
        for (int half = 0; half < 2; ++half) {
            const int iy = half ? iyB : iyA;
            f32x4 c0 = half ? aB0 : aA0;
            f32x4 c1 = half ? aB1 : aA1;
            float s[4];
            #pragma unroll
            for (int reg = 0; reg < 4; ++reg)
                s[reg] = fmaxf(c0[reg] + bb0, 0.f) * wv0 + fmaxf(c1[reg] + bb1, 0.f) * wv1;
            #pragma unroll
            for (int m = 1; m < 16; m <<= 1) {
                #pragma unroll
                for (int reg = 0; reg < 4; ++reg)
                    s[reg] += __shfl_xor(s[reg], m, 64);
            }
            if (r4 < 4) {
                const int ix = g16 * 4 + r4;
                const int Y = ty0 + iy, X = tx0 + ix;
                out[(((size_t)b * IMH + Y) * IMW + X) * NKP + n] = s[r4] + sFsum[iy * TILE + ix];
            }
        }
    }
}

// ---------------- Fallback (R1 fused fp32 VALU kernel), used if ws too small ----------------
#define PITCH 33
__global__ void __launch_bounds__(256)
ckp_fused_kernel(const float* __restrict__ x,
                 const float* __restrict__ w2, const float* __restrict__ b2,
                 const float* __restrict__ wa, const float* __restrict__ ba,
                 const float* __restrict__ wb, const float* __restrict__ bb,
                 const float* __restrict__ Wp,
                 float* __restrict__ out)
{
    __shared__ float sH[HALO * HALO * PITCH];
    __shared__ float sFsum[TILE * TILE];
    __shared__ float sWv[CH];

    const int tid  = threadIdx.x;
    const int tile = blockIdx.x;
    const int b    = blockIdx.y;
    const int n    = blockIdx.z;
    const int ty0  = (tile / (IMW / TILE)) * TILE;
    const int tx0  = (tile % (IMW / TILE)) * TILE;

    if (tid < CH) {
        const float* wp = Wp + (n * CH + tid) * CH;
        float s = 0.f;
        #pragma unroll
        for (int d = 0; d < CH; ++d) s += wp[d];
        sWv[tid] = s;
    }
    const float* wan = wa + n * CH * CH;
    const float* ban = ba + n * CH;

    for (int p = tid; p < HALO * HALO; p += 256) {
        const int hy = p / HALO, hx = p % HALO;
        const int Y = ty0 + hy - 1, X = tx0 + hx - 1;
        float* dst = &sH[p * PITCH];
        if (Y >= 0 && Y < IMH && X >= 0 && X < IMW) {
            const float* xp = x + (((size_t)b * IMH + Y) * IMW + X) * CH;
            float xv[CH];
            #pragma unroll
            for (int e = 0; e < CH; e += 4) {
                float4 v = *(const float4*)(xp + e);
                xv[e] = v.x; xv[e+1] = v.y; xv[e+2] = v.z; xv[e+3] = v.w;
            }
            float f[CH];
            #pragma unroll
            for (int c = 0; c < CH; ++c) f[c] = b2[c];
            #pragma unroll
            for (int e = 0; e < CH; ++e) {
                const float xe = xv[e];
                const float* wr = w2 + e * CH;
                #pragma unroll
                for (int c = 0; c < CH; ++c) f[c] = fmaf(xe, wr[c], f[c]);
            }
            float fs = 0.f;
            #pragma unroll
            for (int c = 0; c < CH; ++c) { f[c] = fmaxf(f[c], 0.f); fs += f[c]; }
            if (hy >= 1 && hy <= TILE && hx >= 1 && hx <= TILE)
                sFsum[(hy - 1) * TILE + (hx - 1)] = fs;
            float h[CH];
            #pragma unroll
            for (int c = 0; c < CH; ++c) h[c] = ban[c];
            #pragma unroll
            for (int e = 0; e < CH; ++e) {
                const float fe = f[e];
                const float* wr = wan + e * CH;
                #pragma unroll
                for (int c = 0; c < CH; ++c) h[c] = fmaf(fe, wr[c], h[c]);
            }
            #pragma unroll
            for (int c = 0; c < CH; ++c) dst[c] = fmaxf(h[c], 0.f);
        } else {
            #pragma unroll
            for (int c = 0; c < CH; ++c) dst[c] = 0.f;
        }
    }
    __syncthreads();

    const int iy = tid / TILE, ix = tid % TILE;
    const float* wbn = wb + n * 9 * CH * CH;
    const float* bbn = bb + n * CH;
    float g[CH];
    #pragma unroll
    for (int c = 0; c < CH; ++c) g[c] = bbn[c];
    for (int dy = 0; dy < 3; ++dy) {
        for (int dx = 0; dx < 3; ++dx) {
            const float* hrow = &sH[((iy + dy) * HALO + (ix + dx)) * PITCH];
            const float* wr0 = wbn + (dy * 3 + dx) * CH * CH;
            #pragma unroll
            for (int e = 0; e < CH; ++e) {
                const float hv = hrow[e];
                const float* wr = wr0 + e * CH;
                #pragma unroll
                for (int c = 0; c < CH; ++c) g[c] = fmaf(hv, wr[c], g[c]);
            }
        }
    }
    float lsum = 0.f;
    #pragma unroll
    for (int c = 0; c < CH; ++c) lsum = fmaf(fmaxf(g[c], 0.f), sWv[c], lsum);
    const int Y = ty0 + iy, X = tx0 + ix;
    out[(((size_t)b * IMH + Y) * IMW + X) * NKP + n] = sFsum[tid] + lsum;
}

extern "C" void kernel_launch(void* const* d_in, const int* in_sizes, int n_in,
                              void* d_out, int out_size, void* d_ws, size_t ws_size,
                              hipStream_t stream) {
    const float* x  = (const float*)d_in[0];
    const float* w2 = (const float*)d_in[1];
    const float* b2 = (const float*)d_in[2];
    const float* wa = (const float*)d_in[3];
    const float* ba = (const float*)d_in[4];
    const float* wb = (const float*)d_in[5];
    const float* bb = (const float*)d_in[6];
    const float* Wp = (const float*)d_in[7];
    float* out = (float*)d_out;

    const size_t npix   = (size_t)BATCH * IMH * IMW;          // 73728
    const size_t f_bytes = npix * CH * sizeof(__bf16);         // 4,718,592
    const size_t need   = f_bytes + npix * sizeof(float);      // + fsum

    if (ws_size >= need) {
        __bf16* f_ws    = (__bf16*)d_ws;
        float*  fsum_ws = (float*)((char*)d_ws + f_bytes);
        f_precompute_kernel<<<dim3(npix / 256), dim3(256), 0, stream>>>(x, w2, b2, f_ws, fsum_ws);
        dim3 grid((IMH / TILE) * (IMW / TILE), BATCH, NKP);
        ckp_mfma_kernel<<<grid, dim3(256), 0, stream>>>(f_ws, fsum_ws, wa, ba, wb, bb, Wp, out);
    } else {
        dim3 grid((IMH / TILE) * (IMW / TILE), BATCH, NKP);
        ckp_fused_kernel<<<grid, dim3(256), 0, stream>>>(x, w2, b2, wa, ba, wb, bb, Wp, out);
    }
}

// Round 3
// 66.852 us; speedup vs baseline: 6.8097x; 1.8489x over previous
//
#include <hip/hip_runtime.h>

// Problem constants
#define BATCH 8
#define IMH 96
#define IMW 96
#define CH 32
#define NKP 21
#define TILE 16
#define HALO 18           // TILE + 2
#define FPITCH 40         // bf16 per pixel in LDS (80 B stride; all b64/b128 patterns saturated-min)
#define NPIX 324          // HALO*HALO
#define NPIX_PAD 336      // 21 m-tiles of 16
#define NGRP 3            // keypoints per block (21 = 7 * 3)

typedef __bf16 bf16x8 __attribute__((ext_vector_type(8)));
typedef __bf16 bf16x4 __attribute__((ext_vector_type(4)));
typedef float  f32x4  __attribute__((ext_vector_type(4)));

static __device__ inline f32x4 mfma16(bf16x8 a, bf16x8 b, f32x4 c) {
    return __builtin_amdgcn_mfma_f32_16x16x32_bf16(a, b, c, 0, 0, 0);
}

// ---------------- Kernel 1: f = relu(x @ w2 + b2) once; bf16 f + fp32 fsum ----
__global__ void __launch_bounds__(256)
f_precompute_kernel(const float* __restrict__ x,
                    const float* __restrict__ w2, const float* __restrict__ b2,
                    __bf16* __restrict__ fout, float* __restrict__ fsum_out)
{
    const int gp = blockIdx.x * 256 + threadIdx.x;
    const float* xp = x + (size_t)gp * CH;
    float xv[CH];
    #pragma unroll
    for (int e = 0; e < CH; e += 4) {
        float4 v = *(const float4*)(xp + e);
        xv[e] = v.x; xv[e+1] = v.y; xv[e+2] = v.z; xv[e+3] = v.w;
    }
    float f[CH];
    #pragma unroll
    for (int c = 0; c < CH; ++c) f[c] = b2[c];
    #pragma unroll
    for (int e = 0; e < CH; ++e) {
        const float xe = xv[e];
        const float* wr = w2 + e * CH;
        #pragma unroll
        for (int c = 0; c < CH; ++c) f[c] = fmaf(xe, wr[c], f[c]);
    }
    float fs = 0.f;
    #pragma unroll
    for (int c = 0; c < CH; ++c) { f[c] = fmaxf(f[c], 0.f); fs += f[c]; }
    #pragma unroll
    for (int q = 0; q < 4; ++q) {
        bf16x8 v;
        #pragma unroll
        for (int j = 0; j < 8; ++j) v[j] = (__bf16)f[q * 8 + j];
        *(bf16x8*)&fout[(size_t)gp * CH + q * 8] = v;
    }
    fsum_out[gp] = fs;
}

// ---------------- Kernel 1b: pre-pack transposed bf16 weight fragments ----
// Fragment f for lane l of keypoint n lives at wfrag[((n*20+f)*64+l)*8 .. +8)
// f=0,1: wa^T halves; f=2+t*2+hf: wb^T tap t half hf. A-frag: row=lane&15 (out-ch
// within half), k=(lane>>4)*8+j (in-ch).
__global__ void __launch_bounds__(64)
wprep_kernel(const float* __restrict__ wa, const float* __restrict__ wb,
             const float* __restrict__ Wp,
             __bf16* __restrict__ wfrag, float* __restrict__ wv)
{
    const int n = blockIdx.x;            // 0..20
    const int lane = threadIdx.x;
    const int r4 = lane & 15, kb = (lane >> 4) * 8;

    const float* wan = wa + n * CH * CH;
    #pragma unroll
    for (int hf = 0; hf < 2; ++hf) {
        bf16x8 v;
        #pragma unroll
        for (int j = 0; j < 8; ++j)
            v[j] = (__bf16)wan[(kb + j) * CH + hf * 16 + r4];
        *(bf16x8*)&wfrag[(((size_t)n * 20 + hf) * 64 + lane) * 8] = v;
    }
    const float* wbn = wb + (size_t)n * 9 * CH * CH;
    for (int t = 0; t < 9; ++t)
        #pragma unroll
        for (int hf = 0; hf < 2; ++hf) {
            bf16x8 v;
            #pragma unroll
            for (int j = 0; j < 8; ++j)
                v[j] = (__bf16)wbn[(t * CH + kb + j) * CH + hf * 16 + r4];
            *(bf16x8*)&wfrag[(((size_t)n * 20 + 2 + t * 2 + hf) * 64 + lane) * 8] = v;
        }
    if (lane < CH) {
        const float* wp = Wp + (n * CH + lane) * CH;
        float s = 0.f;
        #pragma unroll
        for (int d = 0; d < CH; ++d) s += wp[d];
        wv[n * CH + lane] = s;
    }
}

// ---------------- Kernel 2: per (tile,b): stage f once, loop 3 keypoints ----
__global__ void __launch_bounds__(256, 3)
ckp_mfma2_kernel(const __bf16* __restrict__ fws, const float* __restrict__ fsum_ws,
                 const __bf16* __restrict__ wfrag, const float* __restrict__ wvws,
                 const float* __restrict__ ba, const float* __restrict__ bb,
                 float* __restrict__ out)
{
    __shared__ __bf16 sF[NPIX_PAD * FPITCH];
    __shared__ __bf16 sH[NPIX_PAD * FPITCH];
    __shared__ float  sFsum[TILE * TILE];

    const int tid  = threadIdx.x;
    const int tile = blockIdx.x;          // 0..35
    const int b    = blockIdx.y;          // 0..7
    const int ty0  = (tile / (IMW / TILE)) * TILE;
    const int tx0  = (tile % (IMW / TILE)) * TILE;

    const int lane = tid & 63;
    const int w    = tid >> 6;            // wave 0..3
    const int r4   = lane & 15;
    const int g16  = lane >> 4;
    const int kb   = g16 * 8;             // K base (elements)
    const int kb4  = g16 * 4;             // C/D row base (channels)

    // ---- stage bf16 f halo into LDS (zero-pad OOB); once per block ----
    for (int i = tid; i < NPIX * 4; i += 256) {
        const int p = i >> 2, q = i & 3;
        const int hy = p / HALO, hx = p % HALO;
        const int Y = ty0 + hy - 1, X = tx0 + hx - 1;
        bf16x8 v;
        if (Y >= 0 && Y < IMH && X >= 0 && X < IMW) {
            v = *(const bf16x8*)&fws[(((size_t)b * IMH + Y) * IMW + X) * CH + q * 8];
        } else {
            #pragma unroll
            for (int j = 0; j < 8; ++j) v[j] = (__bf16)0.f;
        }
        *(bf16x8*)&sF[p * FPITCH + q * 8] = v;
    }
    if (tid < 48) {  // zero 12 pad pixels
        bf16x8 z;
        #pragma unroll
        for (int j = 0; j < 8; ++j) z[j] = (__bf16)0.f;
        *(bf16x8*)&sF[(NPIX + (tid >> 2)) * FPITCH + (tid & 3) * 8] = z;
    }
    {
        const int iy = tid >> 4, ix = tid & 15;
        sFsum[tid] = fsum_ws[((size_t)b * IMH + ty0 + iy) * IMW + tx0 + ix];
    }
    __syncthreads();

    for (int ni = 0; ni < NGRP; ++ni) {
        const int n = blockIdx.z * NGRP + ni;
        const __bf16* wf = wfrag + (size_t)n * 20 * 64 * 8;

        // pre-packed weight fragments (coalesced b128, L2-hot)
        bf16x8 wafr0 = *(const bf16x8*)&wf[((size_t)0 * 64 + lane) * 8];
        bf16x8 wafr1 = *(const bf16x8*)&wf[((size_t)1 * 64 + lane) * 8];
        bf16x8 wbfr[9][2];
        #pragma unroll
        for (int t = 0; t < 9; ++t)
            #pragma unroll
            for (int hf = 0; hf < 2; ++hf)
                wbfr[t][hf] = *(const bf16x8*)&wf[((size_t)(2 + t * 2 + hf) * 64 + lane) * 8];

        const f32x4 ba0 = *(const f32x4*)&ba[n * CH + kb4];
        const f32x4 ba1 = *(const f32x4*)&ba[n * CH + 16 + kb4];
        const f32x4 bb0 = *(const f32x4*)&bb[n * CH + kb4];
        const f32x4 bb1 = *(const f32x4*)&bb[n * CH + 16 + kb4];
        const f32x4 wv0 = *(const f32x4*)&wvws[n * CH + kb4];
        const f32x4 wv1 = *(const f32x4*)&wvws[n * CH + 16 + kb4];

        if (ni) __syncthreads();   // prev conv reads of sH done before overwrite

        // ---- h-phase: h^T = relu(wa^T @ f^T + ba); lane -> (pixel r4, ch kb4..) ----
        for (int t = w; t < 21; t += 4) {
            const int p = t * 16 + r4;
            bf16x8 ffr = *(const bf16x8*)&sF[p * FPITCH + kb];
            f32x4 a0 = {0.f, 0.f, 0.f, 0.f};
            f32x4 a1 = {0.f, 0.f, 0.f, 0.f};
            a0 = mfma16(wafr0, ffr, a0);
            a1 = mfma16(wafr1, ffr, a1);
            bf16x4 h0, h1;
            #pragma unroll
            for (int r = 0; r < 4; ++r) {
                h0[r] = (__bf16)fmaxf(a0[r] + ba0[r], 0.f);
                h1[r] = (__bf16)fmaxf(a1[r] + ba1[r], 0.f);
            }
            *(bf16x4*)&sH[p * FPITCH + kb4]      = h0;   // ch kb4..kb4+3
            *(bf16x4*)&sH[p * FPITCH + 16 + kb4] = h1;   // ch 16+kb4..
        }
        __syncthreads();

        // ---- conv: 6 input rows x 3 dx reads feed 72 MFMA; acc[oy-w4][half] ----
        const int w4 = w * 4;
        f32x4 acc[4][2];
        #pragma unroll
        for (int ai = 0; ai < 4; ++ai) {
            acc[ai][0] = (f32x4){0.f, 0.f, 0.f, 0.f};
            acc[ai][1] = (f32x4){0.f, 0.f, 0.f, 0.f};
        }
        #pragma unroll
        for (int dx = 0; dx < 3; ++dx) {
            #pragma unroll
            for (int k = 0; k < 6; ++k) {            // input halo row hy = w4+k
                const int hy = w4 + k;
                bf16x8 hfr = *(const bf16x8*)&sH[(hy * HALO + r4 + dx) * FPITCH + kb];
                #pragma unroll
                for (int dy = 0; dy < 3; ++dy) {
                    const int ai = k - dy;           // output row oy = w4 + k - dy
                    if (ai >= 0 && ai < 4) {
                        acc[ai][0] = mfma16(wbfr[dy * 3 + dx][0], hfr, acc[ai][0]);
                        acc[ai][1] = mfma16(wbfr[dy * 3 + dx][1], hfr, acc[ai][1]);
                    }
                }
            }
        }

        // ---- epilogue: lsum = relu(g+bb).wv ; reduce over g16 groups; store ----
        #pragma unroll
        for (int ai = 0; ai < 4; ++ai) {
            float s = 0.f;
            #pragma unroll
            for (int r = 0; r < 4; ++r) {
                s += fmaxf(acc[ai][0][r] + bb0[r], 0.f) * wv0[r];
                s += fmaxf(acc[ai][1][r] + bb1[r], 0.f) * wv1[r];
            }
            s += __shfl_xor(s, 16);
            s += __shfl_xor(s, 32);
            if (g16 == 0) {
                const int oy = w4 + ai;
                out[(((size_t)b * IMH + ty0 + oy) * IMW + tx0 + r4) * NKP + n]
                    = s + sFsum[oy * TILE + r4];
            }
        }
    }
}

// ---------------- Fallback (R1 fused fp32 VALU kernel) ----------------
#define PITCH 33
__global__ void __launch_bounds__(256)
ckp_fused_kernel(const float* __restrict__ x,
                 const float* __restrict__ w2, const float* __restrict__ b2,
                 const float* __restrict__ wa, const float* __restrict__ ba,
                 const float* __restrict__ wb, const float* __restrict__ bb,
                 const float* __restrict__ Wp,
                 float* __restrict__ out)
{
    __shared__ float sH[HALO * HALO * PITCH];
    __shared__ float sFsum[TILE * TILE];
    __shared__ float sWv[CH];

    const int tid  = threadIdx.x;
    const int tile = blockIdx.x;
    const int b    = blockIdx.y;
    const int n    = blockIdx.z;
    const int ty0  = (tile / (IMW / TILE)) * TILE;
    const int tx0  = (tile % (IMW / TILE)) * TILE;

    if (tid < CH) {
        const float* wp = Wp + (n * CH + tid) * CH;
        float s = 0.f;
        #pragma unroll
        for (int d = 0; d < CH; ++d) s += wp[d];
        sWv[tid] = s;
    }
    const float* wan = wa + n * CH * CH;
    const float* ban = ba + n * CH;

    for (int p = tid; p < HALO * HALO; p += 256) {
        const int hy = p / HALO, hx = p % HALO;
        const int Y = ty0 + hy - 1, X = tx0 + hx - 1;
        float* dst = &sH[p * PITCH];
        if (Y >= 0 && Y < IMH && X >= 0 && X < IMW) {
            const float* xp = x + (((size_t)b * IMH + Y) * IMW + X) * CH;
            float xv[CH];
            #pragma unroll
            for (int e = 0; e < CH; e += 4) {
                float4 v = *(const float4*)(xp + e);
                xv[e] = v.x; xv[e+1] = v.y; xv[e+2] = v.z; xv[e+3] = v.w;
            }
            float f[CH];
            #pragma unroll
            for (int c = 0; c < CH; ++c) f[c] = b2[c];
            #pragma unroll
            for (int e = 0; e < CH; ++e) {
                const float xe = xv[e];
                const float* wr = w2 + e * CH;
                #pragma unroll
                for (int c = 0; c < CH; ++c) f[c] = fmaf(xe, wr[c], f[c]);
            }
            float fs = 0.f;
            #pragma unroll
            for (int c = 0; c < CH; ++c) { f[c] = fmaxf(f[c], 0.f); fs += f[c]; }
            if (hy >= 1 && hy <= TILE && hx >= 1 && hx <= TILE)
                sFsum[(hy - 1) * TILE + (hx - 1)] = fs;
            float h[CH];
            #pragma unroll
            for (int c = 0; c < CH; ++c) h[c] = ban[c];
            #pragma unroll
            for (int e = 0; e < CH; ++e) {
                const float fe = f[e];
                const float* wr = wan + e * CH;
                #pragma unroll
                for (int c = 0; c < CH; ++c) h[c] = fmaf(fe, wr[c], h[c]);
            }
            #pragma unroll
            for (int c = 0; c < CH; ++c) dst[c] = fmaxf(h[c], 0.f);
        } else {
            #pragma unroll
            for (int c = 0; c < CH; ++c) dst[c] = 0.f;
        }
    }
    __syncthreads();

    const int iy = tid / TILE, ix = tid % TILE;
    const float* wbn = wb + n * 9 * CH * CH;
    const float* bbn = bb + n * CH;
    float g[CH];
    #pragma unroll
    for (int c = 0; c < CH; ++c) g[c] = bbn[c];
    for (int dy = 0; dy < 3; ++dy) {
        for (int dx = 0; dx < 3; ++dx) {
            const float* hrow = &sH[((iy + dy) * HALO + (ix + dx)) * PITCH];
            const float* wr0 = wbn + (dy * 3 + dx) * CH * CH;
            #pragma unroll
            for (int e = 0; e < CH; ++e) {
                const float hv = hrow[e];
                const float* wr = wr0 + e * CH;
                #pragma unroll
                for (int c = 0; c < CH; ++c) g[c] = fmaf(hv, wr[c], g[c]);
            }
        }
    }
    float lsum = 0.f;
    #pragma unroll
    for (int c = 0; c < CH; ++c) lsum = fmaf(fmaxf(g[c], 0.f), sWv[c], lsum);
    const int Y = ty0 + iy, X = tx0 + ix;
    out[(((size_t)b * IMH + Y) * IMW + X) * NKP + n] = sFsum[tid] + lsum;
}

extern "C" void kernel_launch(void* const* d_in, const int* in_sizes, int n_in,
                              void* d_out, int out_size, void* d_ws, size_t ws_size,
                              hipStream_t stream) {
    const float* x  = (const float*)d_in[0];
    const float* w2 = (const float*)d_in[1];
    const float* b2 = (const float*)d_in[2];
    const float* wa = (const float*)d_in[3];
    const float* ba = (const float*)d_in[4];
    const float* wb = (const float*)d_in[5];
    const float* bb = (const float*)d_in[6];
    const float* Wp = (const float*)d_in[7];
    float* out = (float*)d_out;

    const size_t npix     = (size_t)BATCH * IMH * IMW;            // 73728
    const size_t f_bytes  = npix * CH * sizeof(__bf16);           // 4,718,592
    const size_t fs_bytes = npix * sizeof(float);                 //   294,912
    const size_t wf_bytes = (size_t)NKP * 20 * 64 * 8 * sizeof(__bf16); // 430,080
    const size_t wv_bytes = (size_t)NKP * CH * sizeof(float);     //     2,688
    const size_t need = f_bytes + fs_bytes + wf_bytes + wv_bytes;

    if (ws_size >= need) {
        __bf16* f_ws    = (__bf16*)d_ws;
        float*  fsum_ws = (float*)((char*)d_ws + f_bytes);
        __bf16* wf_ws   = (__bf16*)((char*)d_ws + f_bytes + fs_bytes);
        float*  wv_ws   = (float*)((char*)d_ws + f_bytes + fs_bytes + wf_bytes);

        f_precompute_kernel<<<dim3(npix / 256), dim3(256), 0, stream>>>(x, w2, b2, f_ws, fsum_ws);
        wprep_kernel<<<dim3(NKP), dim3(64), 0, stream>>>(wa, wb, Wp, wf_ws, wv_ws);
        dim3 grid((IMH / TILE) * (IMW / TILE), BATCH, NKP / NGRP); // 36 x 8 x 7
        ckp_mfma2_kernel<<<grid, dim3(256), 0, stream>>>(f_ws, fsum_ws, wf_ws, wv_ws, ba, bb, out);
    } else {
        dim3 grid((IMH / TILE) * (IMW / TILE), BATCH, NKP);
        ckp_fused_kernel<<<grid, dim3(256), 0, stream>>>(x, w2, b2, wa, ba, wb, bb, Wp, out);
    }
}

// Round 5
// 54.365 us; speedup vs baseline: 8.3739x; 1.2297x over previous
//
#include <hip/hip_runtime.h>

// Problem constants
#define BATCH 8
#define IMH 96
#define IMW 96
#define CH 32
#define NKP 21
#define TILE 16
#define HALO 18
#define FPITCH 40         // bf16 per pixel in LDS (80 B stride)
#define NPIX 324          // HALO*HALO
#define NPIX_PAD 336      // 21 m-tiles of 16
#define NGRP 3            // keypoints per block
#define FBLK 1152         // f-precompute blocks (73728 px / 64)

typedef __bf16 bf16x8 __attribute__((ext_vector_type(8)));
typedef __bf16 bf16x4 __attribute__((ext_vector_type(4)));
typedef float  f32x4  __attribute__((ext_vector_type(4)));

static __device__ inline f32x4 mfma16(bf16x8 a, bf16x8 b, f32x4 c) {
    return __builtin_amdgcn_mfma_f32_16x16x32_bf16(a, b, c, 0, 0, 0);
}

// ---------------- Prep: f = relu(x@w2+b2) (blocks 0..1151) + weight pack (1152..1172) ----
__global__ void __launch_bounds__(64)
prep_kernel(const float* __restrict__ x,
            const float* __restrict__ w2, const float* __restrict__ b2,
            const float* __restrict__ wa, const float* __restrict__ wb,
            const float* __restrict__ Wp,
            __bf16* __restrict__ fout, float* __restrict__ fsum_out,
            __bf16* __restrict__ wfrag, float* __restrict__ wv)
{
    const int bx = blockIdx.x;
    const int lane = threadIdx.x;
    if (bx < FBLK) {
        const int gp = bx * 64 + lane;
        const float* xp = x + (size_t)gp * CH;
        float xv[CH];
        #pragma unroll
        for (int e = 0; e < CH; e += 4) {
            float4 v = *(const float4*)(xp + e);
            xv[e] = v.x; xv[e+1] = v.y; xv[e+2] = v.z; xv[e+3] = v.w;
        }
        float f[CH];
        #pragma unroll
        for (int c = 0; c < CH; ++c) f[c] = b2[c];
        #pragma unroll
        for (int e = 0; e < CH; ++e) {
            const float xe = xv[e];
            const float* wr = w2 + e * CH;
            #pragma unroll
            for (int c = 0; c < CH; ++c) f[c] = fmaf(xe, wr[c], f[c]);
        }
        float fs = 0.f;
        #pragma unroll
        for (int c = 0; c < CH; ++c) { f[c] = fmaxf(f[c], 0.f); fs += f[c]; }
        #pragma unroll
        for (int q = 0; q < 4; ++q) {
            bf16x8 v;
            #pragma unroll
            for (int j = 0; j < 8; ++j) v[j] = (__bf16)f[q * 8 + j];
            *(bf16x8*)&fout[(size_t)gp * CH + q * 8] = v;
        }
        fsum_out[gp] = fs;
    } else {
        const int n = bx - FBLK;             // 0..20
        const int r4 = lane & 15, kb = (lane >> 4) * 8;
        const float* wan = wa + n * CH * CH;
        #pragma unroll
        for (int hf = 0; hf < 2; ++hf) {
            bf16x8 v;
            #pragma unroll
            for (int j = 0; j < 8; ++j)
                v[j] = (__bf16)wan[(kb + j) * CH + hf * 16 + r4];   // wa^T fragment
            *(bf16x8*)&wfrag[(((size_t)n * 20 + hf) * 64 + lane) * 8] = v;
        }
        const float* wbn = wb + (size_t)n * 9 * CH * CH;
        for (int t = 0; t < 9; ++t)
            #pragma unroll
            for (int hf = 0; hf < 2; ++hf) {
                bf16x8 v;
                #pragma unroll
                for (int j = 0; j < 8; ++j)
                    v[j] = (__bf16)wbn[(t * CH + kb + j) * CH + hf * 16 + r4];
                *(bf16x8*)&wfrag[(((size_t)n * 20 + 2 + t * 2 + hf) * 64 + lane) * 8] = v;
            }
        if (lane < CH) {
            const float* wp = Wp + (n * CH + lane) * CH;
            float s = 0.f;
            #pragma unroll
            for (int d = 0; d < CH; ++d) s += wp[d];
            wv[n * CH + lane] = s;
        }
    }
}

// ---------------- Main: shared sH + barriers (R3-proven), f read from global ----
__global__ void __launch_bounds__(256, 4)
ckp_mfma4_kernel(const __bf16* __restrict__ fws, const float* __restrict__ fsum_ws,
                 const __bf16* __restrict__ wfrag, const float* __restrict__ wvws,
                 const float* __restrict__ ba, const float* __restrict__ bb,
                 float* __restrict__ out)
{
    __shared__ __bf16 sH[NPIX_PAD * FPITCH];   // 26,880 B

    const int tid  = threadIdx.x;
    const int tile = blockIdx.x;          // 0..35
    const int b    = blockIdx.y;          // 0..7
    const int ty0  = (tile / (IMW / TILE)) * TILE;
    const int tx0  = (tile % (IMW / TILE)) * TILE;

    const int lane = tid & 63;
    const int w    = tid >> 6;            // wave 0..3
    const int r4   = lane & 15;
    const int g16  = lane >> 4;
    const int kb   = g16 * 8;             // K base (in-ch)
    const int kb4  = g16 * 4;             // D row base (out-ch)
    const int w4   = w * 4;

    // ---- hoisted h-phase addressing: i-th m-tile t = w + 4i, pixel p = t*16 + r4 ----
    int voff[6]; unsigned dmask = 0;
    #pragma unroll
    for (int i = 0; i < 6; ++i) {
        const int t  = w + 4 * i;
        const int p  = t * 16 + r4;                 // 0..335 (for t<=20)
        const int hy = p / HALO, hx = p % HALO;
        const int Y  = ty0 + hy - 1, X = tx0 + hx - 1;
        const bool dv = (t <= 20) & (hy < HALO) & (Y >= 0) & (Y < IMH) & (X >= 0) & (X < IMW);
        const int Yc = min(max(Y, 0), IMH - 1), Xc = min(max(X, 0), IMW - 1);
        voff[i] = ((b * IMH + Yc) * IMW + Xc) * CH + kb;
        dmask |= (dv ? 1u : 0u) << i;
    }

    for (int ni = 0; ni < NGRP; ++ni) {
        const int n = blockIdx.z * NGRP + ni;
        const __bf16* wf = wfrag + (size_t)n * 20 * 64 * 8;
        bf16x8 wafr0 = *(const bf16x8*)&wf[((size_t)0 * 64 + lane) * 8];
        bf16x8 wafr1 = *(const bf16x8*)&wf[((size_t)1 * 64 + lane) * 8];
        const f32x4 ba0 = *(const f32x4*)&ba[n * CH + kb4];
        const f32x4 ba1 = *(const f32x4*)&ba[n * CH + 16 + kb4];

        if (ni) __syncthreads();   // prev conv reads of sH done before overwrite

        // ---- h-phase: h^T = relu(wa^T @ f^T + ba); f from global (coalesced) ----
        #pragma unroll
        for (int i = 0; i < 6; ++i) {
            const int t = w + 4 * i;               // wave-uniform
            if (t <= 20) {
                bf16x8 v = *(const bf16x8*)&fws[voff[i]];
                const bool dv = (dmask >> i) & 1;
                if (!dv) {
                    #pragma unroll
                    for (int j = 0; j < 8; ++j) v[j] = (__bf16)0.f;
                }
                const f32x4 z = {0.f, 0.f, 0.f, 0.f};
                f32x4 a0 = mfma16(wafr0, v, z);
                f32x4 a1 = mfma16(wafr1, v, z);
                const int p = t * 16 + r4;
                bf16x4 h0, h1;
                #pragma unroll
                for (int r = 0; r < 4; ++r) {
                    h0[r] = dv ? (__bf16)fmaxf(a0[r] + ba0[r], 0.f) : (__bf16)0.f;
                    h1[r] = dv ? (__bf16)fmaxf(a1[r] + ba1[r], 0.f) : (__bf16)0.f;
                }
                *(bf16x4*)&sH[p * FPITCH + kb4]      = h0;
                *(bf16x4*)&sH[p * FPITCH + 16 + kb4] = h1;
            }
        }
        __syncthreads();

        // ---- conv: 18 LDS b128 reads feed 72 MFMA; wb frags streamed per dx ----
        f32x4 acc[4][2];
        #pragma unroll
        for (int ai = 0; ai < 4; ++ai) {
            acc[ai][0] = (f32x4){0.f, 0.f, 0.f, 0.f};
            acc[ai][1] = (f32x4){0.f, 0.f, 0.f, 0.f};
        }
        #pragma unroll
        for (int dx = 0; dx < 3; ++dx) {
            bf16x8 wt[3][2];
            #pragma unroll
            for (int dy = 0; dy < 3; ++dy)
                #pragma unroll
                for (int hf = 0; hf < 2; ++hf)
                    wt[dy][hf] = *(const bf16x8*)&wf[((size_t)(2 + (dy * 3 + dx) * 2 + hf) * 64 + lane) * 8];
            #pragma unroll
            for (int k = 0; k < 6; ++k) {          // global halo row hy = w4 + k
                bf16x8 hfr = *(const bf16x8*)&sH[((w4 + k) * HALO + r4 + dx) * FPITCH + kb];
                #pragma unroll
                for (int dy = 0; dy < 3; ++dy) {
                    const int ai = k - dy;         // output row oy = w4 + ai
                    if (ai >= 0 && ai < 4) {
                        acc[ai][0] = mfma16(wt[dy][0], hfr, acc[ai][0]);
                        acc[ai][1] = mfma16(wt[dy][1], hfr, acc[ai][1]);
                    }
                }
            }
        }

        // ---- epilogue: lsum = relu(g+bb).wv; reduce over g16; add fsum; store ----
        const f32x4 bb0 = *(const f32x4*)&bb[n * CH + kb4];
        const f32x4 bb1 = *(const f32x4*)&bb[n * CH + 16 + kb4];
        const f32x4 wv0 = *(const f32x4*)&wvws[n * CH + kb4];
        const f32x4 wv1 = *(const f32x4*)&wvws[n * CH + 16 + kb4];
        #pragma unroll
        for (int ai = 0; ai < 4; ++ai) {
            float s = 0.f;
            #pragma unroll
            for (int r = 0; r < 4; ++r) {
                s += fmaxf(acc[ai][0][r] + bb0[r], 0.f) * wv0[r];
                s += fmaxf(acc[ai][1][r] + bb1[r], 0.f) * wv1[r];
            }
            s += __shfl_xor(s, 16);
            s += __shfl_xor(s, 32);
            if (g16 == 0) {
                const int gp = (b * IMH + ty0 + w4 + ai) * IMW + tx0 + r4;
                out[(size_t)gp * NKP + n] = s + fsum_ws[gp];
            }
        }
    }
}

// ---------------- Fallback (R1 fused fp32 VALU kernel) ----------------
#define PITCH 33
__global__ void __launch_bounds__(256)
ckp_fused_kernel(const float* __restrict__ x,
                 const float* __restrict__ w2, const float* __restrict__ b2,
                 const float* __restrict__ wa, const float* __restrict__ ba,
                 const float* __restrict__ wb, const float* __restrict__ bb,
                 const float* __restrict__ Wp,
                 float* __restrict__ out)
{
    __shared__ float sH[HALO * HALO * PITCH];
    __shared__ float sFsum[TILE * TILE];
    __shared__ float sWv[CH];

    const int tid  = threadIdx.x;
    const int tile = blockIdx.x;
    const int b    = blockIdx.y;
    const int n    = blockIdx.z;
    const int ty0  = (tile / (IMW / TILE)) * TILE;
    const int tx0  = (tile % (IMW / TILE)) * TILE;

    if (tid < CH) {
        const float* wp = Wp + (n * CH + tid) * CH;
        float s = 0.f;
        #pragma unroll
        for (int d = 0; d < CH; ++d) s += wp[d];
        sWv[tid] = s;
    }
    const float* wan = wa + n * CH * CH;
    const float* ban = ba + n * CH;

    for (int p = tid; p < HALO * HALO; p += 256) {
        const int hy = p / HALO, hx = p % HALO;
        const int Y = ty0 + hy - 1, X = tx0 + hx - 1;
        float* dst = &sH[p * PITCH];
        if (Y >= 0 && Y < IMH && X >= 0 && X < IMW) {
            const float* xp = x + (((size_t)b * IMH + Y) * IMW + X) * CH;
            float xv[CH];
            #pragma unroll
            for (int e = 0; e < CH; e += 4) {
                float4 v = *(const float4*)(xp + e);
                xv[e] = v.x; xv[e+1] = v.y; xv[e+2] = v.z; xv[e+3] = v.w;
            }
            float f[CH];
            #pragma unroll
            for (int c = 0; c < CH; ++c) f[c] = b2[c];
            #pragma unroll
            for (int e = 0; e < CH; ++e) {
                const float xe = xv[e];
                const float* wr = w2 + e * CH;
                #pragma unroll
                for (int c = 0; c < CH; ++c) f[c] = fmaf(xe, wr[c], f[c]);
            }
            float fs = 0.f;
            #pragma unroll
            for (int c = 0; c < CH; ++c) { f[c] = fmaxf(f[c], 0.f); fs += f[c]; }
            if (hy >= 1 && hy <= TILE && hx >= 1 && hx <= TILE)
                sFsum[(hy - 1) * TILE + (hx - 1)] = fs;
            float h[CH];
            #pragma unroll
            for (int c = 0; c < CH; ++c) h[c] = ban[c];
            #pragma unroll
            for (int e = 0; e < CH; ++e) {
                const float fe = f[e];
                const float* wr = wan + e * CH;
                #pragma unroll
                for (int c = 0; c < CH; ++c) h[c] = fmaf(fe, wr[c], h[c]);
            }
            #pragma unroll
            for (int c = 0; c < CH; ++c) dst[c] = fmaxf(h[c], 0.f);
        } else {
            #pragma unroll
            for (int c = 0; c < CH; ++c) dst[c] = 0.f;
        }
    }
    __syncthreads();

    const int iy = tid / TILE, ix = tid % TILE;
    const float* wbn = wb + n * 9 * CH * CH;
    const float* bbn = bb + n * CH;
    float g[CH];
    #pragma unroll
    for (int c = 0; c < CH; ++c) g[c] = bbn[c];
    for (int dy = 0; dy < 3; ++dy) {
        for (int dx = 0; dx < 3; ++dx) {
            const float* hrow = &sH[((iy + dy) * HALO + (ix + dx)) * PITCH];
            const float* wr0 = wbn + (dy * 3 + dx) * CH * CH;
            #pragma unroll
            for (int e = 0; e < CH; ++e) {
                const float hv = hrow[e];
                const float* wr = wr0 + e * CH;
                #pragma unroll
                for (int c = 0; c < CH; ++c) g[c] = fmaf(hv, wr[c], g[c]);
            }
        }
    }
    float lsum = 0.f;
    #pragma unroll
    for (int c = 0; c < CH; ++c) lsum = fmaf(fmaxf(g[c], 0.f), sWv[c], lsum);
    const int Y = ty0 + iy, X = tx0 + ix;
    out[(((size_t)b * IMH + Y) * IMW + X) * NKP + n] = sFsum[tid] + lsum;
}

extern "C" void kernel_launch(void* const* d_in, const int* in_sizes, int n_in,
                              void* d_out, int out_size, void* d_ws, size_t ws_size,
                              hipStream_t stream) {
    const float* x  = (const float*)d_in[0];
    const float* w2 = (const float*)d_in[1];
    const float* b2 = (const float*)d_in[2];
    const float* wa = (const float*)d_in[3];
    const float* ba = (const float*)d_in[4];
    const float* wb = (const float*)d_in[5];
    const float* bb = (const float*)d_in[6];
    const float* Wp = (const float*)d_in[7];
    float* out = (float*)d_out;

    const size_t npix     = (size_t)BATCH * IMH * IMW;                  // 73728
    const size_t f_bytes  = npix * CH * sizeof(__bf16);                 // 4,718,592
    const size_t fs_bytes = npix * sizeof(float);                       //   294,912
    const size_t wf_bytes = (size_t)NKP * 20 * 64 * 8 * sizeof(__bf16); //   430,080
    const size_t wv_bytes = (size_t)NKP * CH * sizeof(float);           //     2,688
    const size_t need = f_bytes + fs_bytes + wf_bytes + wv_bytes;

    if (ws_size >= need) {
        __bf16* f_ws    = (__bf16*)d_ws;
        float*  fsum_ws = (float*)((char*)d_ws + f_bytes);
        __bf16* wf_ws   = (__bf16*)((char*)d_ws + f_bytes + fs_bytes);
        float*  wv_ws   = (float*)((char*)d_ws + f_bytes + fs_bytes + wf_bytes);

        prep_kernel<<<dim3(FBLK + NKP), dim3(64), 0, stream>>>(
            x, w2, b2, wa, wb, Wp, f_ws, fsum_ws, wf_ws, wv_ws);
        dim3 grid((IMH / TILE) * (IMW / TILE), BATCH, NKP / NGRP); // 36 x 8 x 7
        ckp_mfma4_kernel<<<grid, dim3(256), 0, stream>>>(f_ws, fsum_ws, wf_ws, wv_ws, ba, bb, out);
    } else {
        dim3 grid((IMH / TILE) * (IMW / TILE), BATCH, NKP);
        ckp_fused_kernel<<<grid, dim3(256), 0, stream>>>(x, w2, b2, wa, ba, wb, bb, Wp, out);
    }
}